// Round 8
// baseline (217.128 us; speedup 1.0000x reference)
//
#include <hip/hip_runtime.h>
#include <math.h>

// DivEncoder: x[N,H] -> per-group (D=512 groups, V=16) conv to U=64, ELU,
// conv U->1, row-wise L2 normalize. All fp32 in/out.
#define D_ 512
#define H_ 8192
#define U_ 64
#define V_ 16
#define N_ 4096
#define DUV (D_ * U_ * V_)     // 524288

// k1 v7: v6 math, register-pressure re-engineered. Theory: launch_bounds
// (512,4) caps VGPR at 128; v6's live set (~115-130 with unroll 2) spilled
// to scratch -> hot-loop scratch traffic immune to occupancy/ILP/instr
// diets. Changes: (1) no unroll; (2) tile16 split into two low-live phases
// (pack HI, then reconstruct hi-floats FROM the packed words to build LO --
// r[8]/lo[8] arrays never exist); (3) staggered prefetch (A-half before
// tile16(A), B-half before tile16(B)) halving prefetch live regs.
// Peak live ~95 VGPR < 128.
#define BG 8                   // groups per block = waves per block
#define RB 512                 // rows per block
#define NI 16                  // iterations (32 rows each)
#define YSTR 12                // 8 used + pad

typedef __bf16 bf16x8 __attribute__((ext_vector_type(8)));
typedef __bf16 bf16x4 __attribute__((ext_vector_type(4)));
typedef float f32x4 __attribute__((ext_vector_type(4)));
typedef unsigned int u32x4 __attribute__((ext_vector_type(4)));

#define LOG2E 1.44269504088896340736f
#define LN2F  0.6931471805599453f

#if __has_builtin(__builtin_amdgcn_exp2f)
#define EXP2(x) __builtin_amdgcn_exp2f(x)
#else
#define EXP2(x) __expf((x) * LN2F)
#endif

__device__ __forceinline__ unsigned rne16(unsigned u) {
    // round-to-nearest-even bf16 in the high 16 bits
    return u + 0x7fffu + ((u >> 16) & 1u);
}
__device__ __forceinline__ unsigned fbits(float f) {
    return __builtin_bit_cast(unsigned, f);
}
__device__ __forceinline__ float ffloat(unsigned u) {
    return __builtin_bit_cast(float, u);
}

// Prep: scale W1 by log2(e), then split fp32 -> hi/lo bf16 ([d][u][v] layout).
__global__ __launch_bounds__(256) void k0_split_w1(const float* __restrict__ W1,
                                                   __bf16* __restrict__ wh) {
    __bf16* wl = wh + DUV;
    const int i4 = (blockIdx.x * 256 + threadIdx.x) * 4;
    f32x4 w = *(const f32x4*)(W1 + i4);
    bf16x4 h, l;
    #pragma unroll
    for (int j = 0; j < 4; ++j) {
        float wf = w[j] * LOG2E;
        __bf16 hh = (__bf16)wf;
        h[j] = hh;
        l[j] = (__bf16)(wf - (float)hh);
    }
    *(bf16x4*)(wh + i4) = h;
    *(bf16x4*)(wl + i4) = l;
}

// Split-precision bf16 MFMA (16x16x32): A packs [w_hi | w_lo] along K:
//   MFMA1 B=[x_hi|x_hi], MFMA2 B=[x_lo|x_lo]; sum = w*x to ~2^-16 rel.
// Layouts (HW-verified): A/B: idx=lane&15, k=(lane>>4)*8+j ;
// C/D: col=lane&15, row=(lane>>4)*4+reg.
template <bool PRESPLIT>
__global__ __launch_bounds__(512, 4) void k1_div_encoder(
        const float* __restrict__ x,
        const float* __restrict__ W1,
        const __bf16* __restrict__ wsplit,
        const float* __restrict__ b1,
        const float* __restrict__ W2,
        const float* __restrict__ b2,
        float* __restrict__ y) {
    __shared__ float yt[RB][YSTR];        // 24 KB

    const int tid  = threadIdx.x;
    const int lane = tid & 63;
    const int wave = __builtin_amdgcn_readfirstlane(tid >> 6);  // 0..7
    const int q    = lane >> 4;
    const int m    = lane & 15;
    const int vbase = (q & 1) * 8;

    const int db = blockIdx.x & 63;       // 0..63 group-slice
    const int nb = blockIdx.x >> 6;       // 0..7 row-chunk (512 rows)
    const int d0 = db * BG;
    const int d  = d0 + wave;             // this wave's group
    const int r0 = nb * RB;

    // ---- per-wave weights, loaded once, resident for all iterations ----
    bf16x8 Af[4];
    f32x4  b1f[4], w2f[4];
    if (PRESPLIT) {
        const __bf16* base = wsplit + (size_t)(q >> 1) * DUV;
        #pragma unroll
        for (int c = 0; c < 4; ++c) {
            Af[c] = *(const bf16x8*)(base +
                ((size_t)d * U_ + c * 16 + m) * V_ + vbase);
        }
    } else {
        #pragma unroll
        for (int c = 0; c < 4; ++c) {
            const float* wp = W1 + ((size_t)d * U_ + c * 16 + m) * V_ + vbase;
            f32x4 w0 = *(const f32x4*)wp;
            f32x4 w1v = *(const f32x4*)(wp + 4);
            float wf[8] = {w0.x, w0.y, w0.z, w0.w, w1v.x, w1v.y, w1v.z, w1v.w};
            bf16x8 a;
            #pragma unroll
            for (int i = 0; i < 8; ++i) {
                float ws = wf[i] * LOG2E;
                __bf16 h = (__bf16)ws;
                __bf16 l = (__bf16)(ws - (float)h);
                a[i] = (q < 2) ? h : l;   // cndmask, branchless
            }
            Af[c] = a;
        }
    }
    #pragma unroll
    for (int c = 0; c < 4; ++c) {
        f32x4 bb = *(const f32x4*)(b1 + (size_t)d * U_ + c * 16 + q * 4);
        b1f[c] = bb * LOG2E;              // h' = log2e*(w.x + b1)
        w2f[c] = *(const f32x4*)(W2 + (size_t)d * U_ + c * 16 + q * 4);
    }
    // bc = b2 - sum_u(w2): partial accumulates w2*(e+1); -sum(w2) fixes it.
    float sw = 0.0f;
    #pragma unroll
    for (int c = 0; c < 4; ++c) {
        sw += w2f[c][0] + w2f[c][1] + w2f[c][2] + w2f[c][3];
    }
    sw += __shfl_xor(sw, 16, 64);
    sw += __shfl_xor(sw, 32, 64);
    const float bcs = b2[d] - sw;

    // one 16-row subtile -> this lane's partial of sum w2*(elu+1).
    // Low-live-range version: HI packed first (transient ~2 regs), lo
    // derived from the packed HI words (hi floats reconstructed via <<16 /
    // &0xffff0000), so no r[8]/lo[8] arrays are ever live.
    auto tile16 = [&](f32x4 x0, f32x4 x1) -> float {
        u32x4 HI;
        #pragma unroll
        for (int w = 0; w < 2; ++w) {
            HI[w]     = __builtin_amdgcn_perm(rne16(fbits(x0[2*w+1])),
                                              rne16(fbits(x0[2*w])), 0x07060302u);
            HI[w + 2] = __builtin_amdgcn_perm(rne16(fbits(x1[2*w+1])),
                                              rne16(fbits(x1[2*w])), 0x07060302u);
        }
        u32x4 LO;
        #pragma unroll
        for (int w = 0; w < 2; ++w) {
            float h0 = ffloat(HI[w] << 16);
            float h1 = ffloat(HI[w] & 0xffff0000u);
            float g0 = ffloat(HI[w + 2] << 16);
            float g1 = ffloat(HI[w + 2] & 0xffff0000u);
            LO[w]     = __builtin_amdgcn_perm(fbits(x0[2*w+1] - h1),
                                              fbits(x0[2*w] - h0), 0x07060302u);
            LO[w + 2] = __builtin_amdgcn_perm(fbits(x1[2*w+1] - g1),
                                              fbits(x1[2*w] - g0), 0x07060302u);
        }
        bf16x8 bhi = __builtin_bit_cast(bf16x8, HI);
        bf16x8 blo = __builtin_bit_cast(bf16x8, LO);

        float p0 = 0.0f, p1 = 0.0f;
        #pragma unroll
        for (int c = 0; c < 4; ++c) {
            f32x4 acc = __builtin_amdgcn_mfma_f32_16x16x32_bf16(Af[c], bhi, b1f[c], 0, 0, 0);
            acc = __builtin_amdgcn_mfma_f32_16x16x32_bf16(Af[c], blo, acc, 0, 0, 0);
            #pragma unroll
            for (int rr = 0; rr < 4; ++rr) {
                float hp = acc[rr];                        // h * log2e
                float t  = EXP2(fminf(hp, 0.0f));          // exp(min(h,0))
                float h1 = __builtin_fmaf(hp, LN2F, 1.0f); // h + 1
                float e1 = fmaxf(h1, t);                   // elu(h) + 1
                if (c < 2) p0 = __builtin_fmaf(w2f[c][rr], e1, p0);
                else       p1 = __builtin_fmaf(w2f[c][rr], e1, p1);
            }
        }
        return p0 + p1;
    };

    // ---- streaming main loop: 2 independent subtiles (rows +0, +16),
    // staggered prefetch: A-half issued before tile16(A), B-half before
    // tile16(B) (>= half-iter latency cover, half the prefetch regs) ----
    const float* baseA = x + (size_t)(r0 + m) * H_ + d * V_ + vbase;
    const float* baseB = baseA + (size_t)16 * H_;
    const size_t stride = (size_t)32 * H_;

    f32x4 a0 = *(const f32x4*)baseA;
    f32x4 a1 = *(const f32x4*)(baseA + 4);
    f32x4 b0 = *(const f32x4*)baseB;
    f32x4 b1v = *(const f32x4*)(baseB + 4);

    #pragma unroll 1
    for (int it = 0; it < NI; ++it) {
        const size_t offn = (size_t)(it + 1 < NI ? it + 1 : it) * stride;
        f32x4 na0 = *(const f32x4*)(baseA + offn);
        f32x4 na1 = *(const f32x4*)(baseA + offn + 4);

        float pA = tile16(a0, a1);

        f32x4 nb0 = *(const f32x4*)(baseB + offn);
        f32x4 nb1 = *(const f32x4*)(baseB + offn + 4);

        float pB = tile16(b0, b1v);

        pA += __shfl_xor(pA, 16, 64);
        pB += __shfl_xor(pB, 16, 64);
        pA += __shfl_xor(pA, 32, 64);
        pB += __shfl_xor(pB, 32, 64);
        if (q == 0) {
            yt[it * 32 + m][wave]      = pA + bcs;
            yt[it * 32 + 16 + m][wave] = pB + bcs;
        }
        a0 = na0; a1 = na1; b0 = nb0; b1v = nb1;
    }
    __syncthreads();

    // ---- y store: thread tid handles row tid (32B per row-slice) ----
    {
        f32x4 v0 = *(const f32x4*)&yt[tid][0];
        f32x4 v1 = *(const f32x4*)&yt[tid][4];
        float* yp = y + (size_t)(r0 + tid) * D_ + d0;
        *(f32x4*)yp = v0;
        *(f32x4*)(yp + 4) = v1;
    }
}

// Kernel 2: row-wise L2 normalize in place. One block (256 threads) per row.
__global__ __launch_bounds__(256) void k2_l2_normalize(float* __restrict__ y) {
    const int n = blockIdx.x;
    const int t = threadIdx.x;
    float* row = y + (size_t)n * D_;

    float v0 = row[t];
    float v1 = row[t + 256];
    float ss = v0 * v0 + v1 * v1;

    #pragma unroll
    for (int off = 32; off > 0; off >>= 1) {
        ss += __shfl_down(ss, off, 64);
    }

    __shared__ float wsum[4];
    if ((t & 63) == 0) wsum[t >> 6] = ss;
    __syncthreads();
    const float tot = wsum[0] + wsum[1] + wsum[2] + wsum[3];

    const float scale = 1.0f / fmaxf(sqrtf(tot), 1e-12f);

    row[t]       = v0 * scale;
    row[t + 256] = v1 * scale;
}

extern "C" void kernel_launch(void* const* d_in, const int* in_sizes, int n_in,
                              void* d_out, int out_size, void* d_ws, size_t ws_size,
                              hipStream_t stream) {
    const float* x  = (const float*)d_in[0];
    const float* W1 = (const float*)d_in[1];
    const float* b1 = (const float*)d_in[2];
    const float* W2 = (const float*)d_in[3];
    const float* b2 = (const float*)d_in[4];
    float* y = (float*)d_out;  // [N, D] fp32

    const dim3 grid((N_ / RB) * (D_ / BG));   // 512 blocks, all co-resident
    if (ws_size >= (size_t)(2 * DUV * sizeof(__bf16))) {
        __bf16* wh = (__bf16*)d_ws;
        k0_split_w1<<<dim3(DUV / 4 / 256), dim3(256), 0, stream>>>(W1, wh);
        k1_div_encoder<true><<<grid, dim3(512), 0, stream>>>(
            x, W1, wh, b1, W2, b2, y);
    } else {
        k1_div_encoder<false><<<grid, dim3(512), 0, stream>>>(
            x, W1, (const __bf16*)nullptr, b1, W2, b2, y);
    }
    k2_l2_normalize<<<dim3(N_), dim3(256), 0, stream>>>(y);
}

// Round 10
// 213.737 us; speedup vs baseline: 1.0159x; 1.0159x over previous
//
#include <hip/hip_runtime.h>
#include <math.h>

// DivEncoder: x[N,H] -> per-group (D=512 groups, V=16) conv to U=64, ELU,
// conv U->1, row-wise L2 normalize. All fp32 in/out.
#define D_ 512
#define H_ 8192
#define U_ 64
#define V_ 16
#define N_ 4096

// k1 v8: v7 structure, ZERO workspace usage. The timed window is dominated
// by 2x512MiB workspace-poison fills (~155us); our ws need was 2MB and the
// presplit saved ~2us. If re-poison is tied to ws being touched, dropping
// all d_ws use removes the fills; if not, we still save k0 + launch gap.
// Weight hi/lo split (scaled by log2e) now runs in k1's prologue, once per
// persistent block, amortized over NI=16 iterations.
#define BG 8                   // groups per block = waves per block
#define RB 512                 // rows per block
#define NI 16                  // iterations (32 rows each)
#define YSTR 12                // 8 used + pad

typedef __bf16 bf16x8 __attribute__((ext_vector_type(8)));
typedef float f32x4 __attribute__((ext_vector_type(4)));
typedef unsigned int u32x4 __attribute__((ext_vector_type(4)));

#define LOG2E 1.44269504088896340736f
#define LN2F  0.6931471805599453f

#if __has_builtin(__builtin_amdgcn_exp2f)
#define EXP2(x) __builtin_amdgcn_exp2f(x)
#else
#define EXP2(x) __expf((x) * LN2F)
#endif

__device__ __forceinline__ unsigned rne16(unsigned u) {
    // round-to-nearest-even bf16 in the high 16 bits
    return u + 0x7fffu + ((u >> 16) & 1u);
}
__device__ __forceinline__ unsigned fbits(float f) {
    return __builtin_bit_cast(unsigned, f);
}
__device__ __forceinline__ float ffloat(unsigned u) {
    return __builtin_bit_cast(float, u);
}

// Split-precision bf16 MFMA (16x16x32): A packs [w_hi | w_lo] along K:
//   MFMA1 B=[x_hi|x_hi], MFMA2 B=[x_lo|x_lo]; sum = w*x to ~2^-16 rel.
// Layouts (HW-verified): A/B: idx=lane&15, k=(lane>>4)*8+j ;
// C/D: col=lane&15, row=(lane>>4)*4+reg.
__global__ __launch_bounds__(512, 4) void k1_div_encoder(
        const float* __restrict__ x,
        const float* __restrict__ W1,
        const float* __restrict__ b1,
        const float* __restrict__ W2,
        const float* __restrict__ b2,
        float* __restrict__ y) {
    __shared__ float yt[RB][YSTR];        // 24 KB

    const int tid  = threadIdx.x;
    const int lane = tid & 63;
    const int wave = __builtin_amdgcn_readfirstlane(tid >> 6);  // 0..7
    const int q    = lane >> 4;
    const int m    = lane & 15;
    const int vbase = (q & 1) * 8;

    const int db = blockIdx.x & 63;       // 0..63 group-slice
    const int nb = blockIdx.x >> 6;       // 0..7 row-chunk (512 rows)
    const int d0 = db * BG;
    const int d  = d0 + wave;             // this wave's group
    const int r0 = nb * RB;

    // ---- per-wave weights: load W1 fp32, scale by log2e, split hi/lo
    // in-registers (once per block, amortized over NI iterations) ----
    bf16x8 Af[4];
    f32x4  b1f[4], w2f[4];
    #pragma unroll
    for (int c = 0; c < 4; ++c) {
        const float* wp = W1 + ((size_t)d * U_ + c * 16 + m) * V_ + vbase;
        f32x4 w0 = *(const f32x4*)wp;
        f32x4 w1v = *(const f32x4*)(wp + 4);
        float wf[8] = {w0.x, w0.y, w0.z, w0.w, w1v.x, w1v.y, w1v.z, w1v.w};
        bf16x8 a;
        #pragma unroll
        for (int i = 0; i < 8; ++i) {
            float ws = wf[i] * LOG2E;
            __bf16 h = (__bf16)ws;
            __bf16 l = (__bf16)(ws - (float)h);
            a[i] = (q < 2) ? h : l;   // cndmask, branchless
        }
        Af[c] = a;
    }
    #pragma unroll
    for (int c = 0; c < 4; ++c) {
        f32x4 bb = *(const f32x4*)(b1 + (size_t)d * U_ + c * 16 + q * 4);
        b1f[c] = bb * LOG2E;              // h' = log2e*(w.x + b1)
        w2f[c] = *(const f32x4*)(W2 + (size_t)d * U_ + c * 16 + q * 4);
    }
    // bc = b2 - sum_u(w2): partial accumulates w2*(e+1); -sum(w2) fixes it.
    float sw = 0.0f;
    #pragma unroll
    for (int c = 0; c < 4; ++c) {
        sw += w2f[c][0] + w2f[c][1] + w2f[c][2] + w2f[c][3];
    }
    sw += __shfl_xor(sw, 16, 64);
    sw += __shfl_xor(sw, 32, 64);
    const float bcs = b2[d] - sw;

    // one 16-row subtile -> this lane's partial of sum w2*(elu+1).
    // Low-live-range: pack HI first, reconstruct hi floats from the packed
    // words (<<16 / &0xffff0000) to build LO -- no r[8]/lo[8] arrays live.
    auto tile16 = [&](f32x4 x0, f32x4 x1) -> float {
        u32x4 HI;
        #pragma unroll
        for (int w = 0; w < 2; ++w) {
            HI[w]     = __builtin_amdgcn_perm(rne16(fbits(x0[2*w+1])),
                                              rne16(fbits(x0[2*w])), 0x07060302u);
            HI[w + 2] = __builtin_amdgcn_perm(rne16(fbits(x1[2*w+1])),
                                              rne16(fbits(x1[2*w])), 0x07060302u);
        }
        u32x4 LO;
        #pragma unroll
        for (int w = 0; w < 2; ++w) {
            float h0 = ffloat(HI[w] << 16);
            float h1 = ffloat(HI[w] & 0xffff0000u);
            float g0 = ffloat(HI[w + 2] << 16);
            float g1 = ffloat(HI[w + 2] & 0xffff0000u);
            LO[w]     = __builtin_amdgcn_perm(fbits(x0[2*w+1] - h1),
                                              fbits(x0[2*w] - h0), 0x07060302u);
            LO[w + 2] = __builtin_amdgcn_perm(fbits(x1[2*w+1] - g1),
                                              fbits(x1[2*w] - g0), 0x07060302u);
        }
        bf16x8 bhi = __builtin_bit_cast(bf16x8, HI);
        bf16x8 blo = __builtin_bit_cast(bf16x8, LO);

        float p0 = 0.0f, p1 = 0.0f;
        #pragma unroll
        for (int c = 0; c < 4; ++c) {
            f32x4 acc = __builtin_amdgcn_mfma_f32_16x16x32_bf16(Af[c], bhi, b1f[c], 0, 0, 0);
            acc = __builtin_amdgcn_mfma_f32_16x16x32_bf16(Af[c], blo, acc, 0, 0, 0);
            #pragma unroll
            for (int rr = 0; rr < 4; ++rr) {
                float hp = acc[rr];                        // h * log2e
                float t  = EXP2(fminf(hp, 0.0f));          // exp(min(h,0))
                float h1 = __builtin_fmaf(hp, LN2F, 1.0f); // h + 1
                float e1 = fmaxf(h1, t);                   // elu(h) + 1
                if (c < 2) p0 = __builtin_fmaf(w2f[c][rr], e1, p0);
                else       p1 = __builtin_fmaf(w2f[c][rr], e1, p1);
            }
        }
        return p0 + p1;
    };

    // ---- streaming main loop: 2 independent subtiles (rows +0, +16),
    // staggered prefetch: A-half before tile16(A), B-half before tile16(B) ----
    const float* baseA = x + (size_t)(r0 + m) * H_ + d * V_ + vbase;
    const float* baseB = baseA + (size_t)16 * H_;
    const size_t stride = (size_t)32 * H_;

    f32x4 a0 = *(const f32x4*)baseA;
    f32x4 a1 = *(const f32x4*)(baseA + 4);
    f32x4 b0 = *(const f32x4*)baseB;
    f32x4 b1v = *(const f32x4*)(baseB + 4);

    #pragma unroll 1
    for (int it = 0; it < NI; ++it) {
        const size_t offn = (size_t)(it + 1 < NI ? it + 1 : it) * stride;
        f32x4 na0 = *(const f32x4*)(baseA + offn);
        f32x4 na1 = *(const f32x4*)(baseA + offn + 4);

        float pA = tile16(a0, a1);

        f32x4 nb0 = *(const f32x4*)(baseB + offn);
        f32x4 nb1 = *(const f32x4*)(baseB + offn + 4);

        float pB = tile16(b0, b1v);

        pA += __shfl_xor(pA, 16, 64);
        pB += __shfl_xor(pB, 16, 64);
        pA += __shfl_xor(pA, 32, 64);
        pB += __shfl_xor(pB, 32, 64);
        if (q == 0) {
            yt[it * 32 + m][wave]      = pA + bcs;
            yt[it * 32 + 16 + m][wave] = pB + bcs;
        }
        a0 = na0; a1 = na1; b0 = nb0; b1v = nb1;
    }
    __syncthreads();

    // ---- y store: thread tid handles row tid (32B per row-slice) ----
    {
        f32x4 v0 = *(const f32x4*)&yt[tid][0];
        f32x4 v1 = *(const f32x4*)&yt[tid][4];
        float* yp = y + (size_t)(r0 + tid) * D_ + d0;
        *(f32x4*)yp = v0;
        *(f32x4*)(yp + 4) = v1;
    }
}

// Kernel 2: row-wise L2 normalize in place. One block (256 threads) per row.
__global__ __launch_bounds__(256) void k2_l2_normalize(float* __restrict__ y) {
    const int n = blockIdx.x;
    const int t = threadIdx.x;
    float* row = y + (size_t)n * D_;

    float v0 = row[t];
    float v1 = row[t + 256];
    float ss = v0 * v0 + v1 * v1;

    #pragma unroll
    for (int off = 32; off > 0; off >>= 1) {
        ss += __shfl_down(ss, off, 64);
    }

    __shared__ float wsum[4];
    if ((t & 63) == 0) wsum[t >> 6] = ss;
    __syncthreads();
    const float tot = wsum[0] + wsum[1] + wsum[2] + wsum[3];

    const float scale = 1.0f / fmaxf(sqrtf(tot), 1e-12f);

    row[t]       = v0 * scale;
    row[t + 256] = v1 * scale;
}

extern "C" void kernel_launch(void* const* d_in, const int* in_sizes, int n_in,
                              void* d_out, int out_size, void* d_ws, size_t ws_size,
                              hipStream_t stream) {
    const float* x  = (const float*)d_in[0];
    const float* W1 = (const float*)d_in[1];
    const float* b1 = (const float*)d_in[2];
    const float* W2 = (const float*)d_in[3];
    const float* b2 = (const float*)d_in[4];
    float* y = (float*)d_out;  // [N, D] fp32

    (void)d_ws; (void)ws_size;  // workspace intentionally untouched

    const dim3 grid((N_ / RB) * (D_ / BG));   // 512 blocks, all co-resident
    k1_div_encoder<<<grid, dim3(512), 0, stream>>>(x, W1, b1, W2, b2, y);
    k2_l2_normalize<<<dim3(N_), dim3(256), 0, stream>>>(y);
}